// Round 10
// baseline (69.861 us; speedup 1.0000x reference)
//
#include <hip/hip_runtime.h>
#include <hip/hip_bf16.h>

// ScatterHorizontal round 10: zero-LDS zero-barrier stream (R8 compute) with
// block = one batch (R6's minimal-fetch mapping). 6 waves x 16-pixel tiles per
// batch; B-fragments gathered directly from global (L1 serves the 6-wave
// reuse); A = prep'd W-fragments (L1-hot). No LDS, no barriers, no staging.
// Slabs are 128B-aligned and block-private -> no cross-XCD line sharing.
// out[b,o,h,w'] = sum_i [0<=w'-d_i<9]( sum_c W[i,o,c]*x_i[b,c,h,w'-d_i] + bias[i,o] )

#define CIN   64
#define COUT  64
#define NOFF  9
#define HW    81
#define SLAB  5184           // f32 per (b,i) slab

typedef short bf16x8 __attribute__((ext_vector_type(8)));
typedef float f32x4  __attribute__((ext_vector_type(4)));

static __device__ __forceinline__ unsigned int f2bf(float v) {
    union { __hip_bfloat16 h; unsigned short u; } cv;
    cv.h = __float2bfloat16(v);
    return (unsigned int)cv.u;
}

// wfrag flat idx = (((i*2 + kt)*4 + ot)*64 + lane)*8 + j
//   value = bf16( W[i][o = 16*ot + (lane&15)][c = 32*kt + 8*(lane>>4) + j] )
// serves as the MFMA A-fragment: row m = o_local = lane&15, k = 8*(lane>>4)+j
__global__ __launch_bounds__(256) void prep_kernel(
    const float* __restrict__ wts,   // [9][64][64] (i,o,c)
    const float* __restrict__ bias,  // [9][64]
    unsigned short* __restrict__ wfrag,
    float* __restrict__ biasEff)     // [9][64] (w,o)
{
    int tid = blockIdx.x * 256 + threadIdx.x;
    int stride = gridDim.x * 256;
    for (int e = tid; e < NOFF * 4096; e += stride) {
        int j  = e & 7;
        int l  = (e >> 3) & 63;
        int ot = (e >> 9) & 3;
        int kt = (e >> 11) & 1;
        int i  = e >> 12;
        int o  = ot * 16 + (l & 15);
        int c  = kt * 32 + (l >> 4) * 8 + j;
        wfrag[e] = (unsigned short)f2bf(wts[(i * COUT + o) * CIN + c]);
    }
    if (blockIdx.x == 0) {
        for (int e = threadIdx.x; e < 9 * COUT; e += 256) {
            int w = e / COUT, o = e - w * COUT;
            int lo = (w - 4 > 0) ? (w - 4) : 0;
            int hi = (w + 4 < 8) ? (w + 4) : 8;
            float s = 0.f;
            for (int i2 = lo; i2 <= hi; ++i2) s += bias[i2 * COUT + o];
            biasEff[e] = s;
        }
    }
}

__global__ __launch_bounds__(384, 6) void scatter_direct_kernel(
    const float* __restrict__ x0, const float* __restrict__ x1,
    const float* __restrict__ x2, const float* __restrict__ x3,
    const float* __restrict__ x4, const float* __restrict__ x5,
    const float* __restrict__ x6, const float* __restrict__ x7,
    const float* __restrict__ x8,
    const unsigned short* __restrict__ wfrag,
    const float* __restrict__ biasEff,
    float* __restrict__ out)
{
    const int b    = blockIdx.x;         // one batch per block
    const int t    = threadIdx.x;
    const int wave = t >> 6;             // pixel tile 0..5 (96 px >= 81)
    const int lane = t & 63;
    const int l15  = lane & 15;
    const int lhi  = lane >> 4;          // k-octet for B, row-quad for C/D

    const int p0     = wave * 16 + l15;  // lane's pixel, 0..95
    const bool pval  = (p0 < 81);
    const int p      = pval ? p0 : 80;   // clamp tail lanes to a safe address
    const int wcol   = p % 9;            // board file w'

    const float* xp[NOFF] = { x0, x1, x2, x3, x4, x5, x6, x7, x8 };

    // accumulators: acc[ot][jj] = D[o = 16ot + 4lhi + jj][pixel col]; init bias
    f32x4 acc[4];
#pragma unroll
    for (int ot = 0; ot < 4; ++ot)
#pragma unroll
        for (int jj = 0; jj < 4; ++jj)
            acc[ot][jj] = biasEff[wcol * COUT + ot * 16 + 4 * lhi + jj];

    // lane-invariant dword offset: channels 8*lhi + j live at +j*81
    const size_t boff = (size_t)b * SLAB + (size_t)(8 * lhi) * HW;

#pragma unroll
    for (int i = 0; i < NOFF; ++i) {
        const int d      = i - 4;
        const bool valid = (unsigned)(wcol - d) < 9u;
        const int q      = valid ? (p - d) : p;   // same h-row, shifted file

        // B-fragment: 16 stride-81 dword gathers (8 per kt), cvt bf16, mask
        const float* base = xp[i] + boff + q;
        bf16x8 xb[2];
#pragma unroll
        for (int kt = 0; kt < 2; ++kt) {
            const float* sp = base + kt * 2592;   // +32 channels
            float f[8];
#pragma unroll
            for (int j = 0; j < 8; ++j) f[j] = sp[j * HW];
            int4 ai;
            ai.x = f2bf(f[0]) | (f2bf(f[1]) << 16);
            ai.y = f2bf(f[2]) | (f2bf(f[3]) << 16);
            ai.z = f2bf(f[4]) | (f2bf(f[5]) << 16);
            ai.w = f2bf(f[6]) | (f2bf(f[7]) << 16);
            if (!valid) { ai.x = 0; ai.y = 0; ai.z = 0; ai.w = 0; }
            xb[kt] = __builtin_bit_cast(bf16x8, ai);
        }

        // A-fragments (prep'd W, L1-hot: 8 KB slice shared by all waves on CU)
#pragma unroll
        for (int kt = 0; kt < 2; ++kt) {
#pragma unroll
            for (int ot = 0; ot < 4; ++ot) {
                bf16x8 aw = *(const bf16x8*)&wfrag[(((i * 2 + kt) * 4 + ot) * 64 + lane) * 8];
                acc[ot] = __builtin_amdgcn_mfma_f32_16x16x32_bf16(aw, xb[kt], acc[ot], 0, 0, 0);
            }
        }
    }

    // store: lane writes its pixel's output column (o-major rows, stride 81)
    if (pval) {
        float* ob = out + ((size_t)b * COUT) * HW + p;
#pragma unroll
        for (int ot = 0; ot < 4; ++ot)
#pragma unroll
            for (int jj = 0; jj < 4; ++jj)
                ob[(ot * 16 + 4 * lhi + jj) * HW] = acc[ot][jj];
    }
}

extern "C" void kernel_launch(void* const* d_in, const int* in_sizes, int n_in,
                              void* d_out, int out_size, void* d_ws, size_t ws_size,
                              hipStream_t stream) {
    const float* x[9];
    for (int i = 0; i < 9; ++i) x[i] = (const float*)d_in[i];
    const float* wts  = (const float*)d_in[9];
    const float* bias = (const float*)d_in[10];
    float* out = (float*)d_out;

    unsigned short* wfrag = (unsigned short*)d_ws;                    // 73728 B
    float* biasEff = (float*)((char*)d_ws + NOFF * 4096 * sizeof(unsigned short));

    prep_kernel<<<144, 256, 0, stream>>>(wts, bias, wfrag, biasEff);
    // one block per batch, 6 waves = 6 pixel tiles of 16 (96 >= 81)
    scatter_direct_kernel<<<1024, 384, 0, stream>>>(
        x[0], x[1], x[2], x[3], x[4], x[5], x[6], x[7], x[8],
        wfrag, biasEff, out);
}

// Round 11
// 48.428 us; speedup vs baseline: 1.4426x; 1.4426x over previous
//
#include <hip/hip_runtime.h>
#include <hip/hip_bf16.h>

// ScatterHorizontal round 11: R6 structure + DEPTH-2 prefetch, 3-buffer LDS
// rotation. At iter i: issue global loads slab i+2 -> regs; ds_write slab i+1
// (landed long ago) -> buf[(i+1)%3]; compute slab i from buf[i%3]; one
// {lgkmcnt(0); barrier}. HBM round-trip gets a FULL iteration to complete ->
// VMEM queue never drains at the barrier (R4-R10 analysis: delivered-BW
// plateau came from per-iter load-issue/land coupling).
// out[b,o,h,w'] = sum_i [0<=w'-d_i<9]( sum_c W[i,o,c]*x_i[b,c,h,w'-d_i] + bias[i,o] )

#define CIN   64
#define COUT  64
#define NOFF  9
#define HW    81
#define SLAB  5184           // f32 per (b,i) slab
#define RSTB  136            // LDS row stride bytes (64 bf16 = 128 + 8 pad)
#define NROW  82             // rows 0..80 data, row 81 = zero row
#define ZR    81
#define BUFB  (NROW * RSTB)  // 11152 B per buffer

typedef short bf16x8 __attribute__((ext_vector_type(8)));
typedef float f32x4  __attribute__((ext_vector_type(4)));

static __device__ __forceinline__ unsigned int f2bf(float v) {
    union { __hip_bfloat16 h; unsigned short u; } cv;
    cv.h = __float2bfloat16(v);
    return (unsigned int)cv.u;
}

// wfrag flat idx = (((i*2 + kt)*4 + ot)*64 + lane)*8 + j
//   value = bf16( W[i][o = 16*ot + (lane&15)][c = 32*kt + 8*(lane>>4) + j] )
__global__ __launch_bounds__(256) void prep_kernel(
    const float* __restrict__ wts,   // [9][64][64] (i,o,c)
    const float* __restrict__ bias,  // [9][64]
    unsigned short* __restrict__ wfrag,
    float* __restrict__ biasEff)     // [9][64] (w,o)
{
    int tid = blockIdx.x * 256 + threadIdx.x;
    int stride = gridDim.x * 256;
    for (int e = tid; e < NOFF * 4096; e += stride) {
        int j  = e & 7;
        int l  = (e >> 3) & 63;
        int ot = (e >> 9) & 3;
        int kt = (e >> 11) & 1;
        int i  = e >> 12;
        int o  = ot * 16 + (l & 15);
        int c  = kt * 32 + (l >> 4) * 8 + j;
        wfrag[e] = (unsigned short)f2bf(wts[(i * COUT + o) * CIN + c]);
    }
    if (blockIdx.x == 0) {
        for (int e = threadIdx.x; e < 9 * COUT; e += 256) {
            int w = e / COUT, o = e - w * COUT;
            int lo = (w - 4 > 0) ? (w - 4) : 0;
            int hi = (w + 4 < 8) ? (w + 4) : 8;
            float s = 0.f;
            for (int i2 = lo; i2 <= hi; ++i2) s += bias[i2 * COUT + o];
            biasEff[e] = s;
        }
    }
}

__global__ __launch_bounds__(256, 4) void scatter_mfma8_kernel(
    const float* __restrict__ x0, const float* __restrict__ x1,
    const float* __restrict__ x2, const float* __restrict__ x3,
    const float* __restrict__ x4, const float* __restrict__ x5,
    const float* __restrict__ x6, const float* __restrict__ x7,
    const float* __restrict__ x8,
    const unsigned short* __restrict__ wfrag,
    const float* __restrict__ biasEff,
    float* __restrict__ out)
{
    __shared__ __align__(16) unsigned char xs[3 * BUFB];   // 33456 B

    const int b    = blockIdx.x;
    const int t    = threadIdx.x;
    const int wid  = t >> 6;
    const int lane = t & 63;
    const int l15  = lane & 15;
    const int lhi  = lane >> 4;      // 0..3
    const int mh   = wid >> 1;       // m-half: rows mh*48 + [0,48)
    const int oh   = wid & 1;        // o-half: cols oh*32 + [0,32)

    // staging role: thread = (g, p); g=3 (t>=243) inactive
    const int g     = t / 81;
    const int p     = t - g * 81;
    const bool stg  = (g < 3);
    const int wbase = p * RSTB + 8 * g;

    const float* xp[NOFF] = { x0, x1, x2, x3, x4, x5, x6, x7, x8 };

    // A-row constants (i-invariant)
    int pAv[3], wAv[3];
#pragma unroll
    for (int mt = 0; mt < 3; ++mt) {
        pAv[mt] = mh * 48 + mt * 16 + l15;
        wAv[mt] = pAv[mt] % 9;
    }

    // accumulators init = biasEff[w'][o]
    f32x4 acc[3][2];
#pragma unroll
    for (int mt = 0; mt < 3; ++mt) {
#pragma unroll
        for (int of = 0; of < 2; ++of) {
            const int ocol = oh * 32 + of * 16 + l15;
#pragma unroll
            for (int jj = 0; jj < 4; ++jj) {
                int pp = mh * 48 + mt * 16 + lhi * 4 + jj;
                if (pp > 80) pp = 80;                    // garbage rows (unstored)
                acc[mt][of][jj] = biasEff[(pp % 9) * COUT + ocol];
            }
        }
    }

    // zero row ZR of all 3 buffers (34 dwords each = 102 total)
    if (t < 102) {
        int nb  = t / 34;
        int dwi = t - nb * 34;
        *(unsigned int*)&xs[nb * BUFB + ZR * RSTB + 4 * dwi] = 0u;
    }

    // staging helpers: load slab -> regs (up to 24 f32); cvt+write regs -> buf
#define LOADS(SET, SRC)                                                         \
    if (stg) {                                                                  \
        const float* _sp = (SRC) + g * 324 + p;                                 \
        _Pragma("unroll")                                                       \
        for (int _k = 0; _k < 5; ++_k) {                                        \
            SET[_k][0] = _sp[0];   SET[_k][1] = _sp[81];                        \
            SET[_k][2] = _sp[162]; SET[_k][3] = _sp[243];                       \
            _sp += 972;                                                         \
        }                                                                       \
        if (g == 0) {                                                           \
            SET[5][0] = _sp[0];   SET[5][1] = _sp[81];                          \
            SET[5][2] = _sp[162]; SET[5][3] = _sp[243];                         \
        }                                                                       \
    }
#define WRITES(SET, NB)                                                         \
    if (stg) {                                                                  \
        unsigned char* _wb = &xs[(NB) * BUFB + wbase];                          \
        _Pragma("unroll")                                                       \
        for (int _k = 0; _k < 5; ++_k) {                                        \
            uint2 _v;                                                           \
            _v.x = f2bf(SET[_k][0]) | (f2bf(SET[_k][1]) << 16);                 \
            _v.y = f2bf(SET[_k][2]) | (f2bf(SET[_k][3]) << 16);                 \
            *(uint2*)(_wb + 24 * _k) = _v;                                      \
        }                                                                       \
        if (g == 0) {                                                           \
            uint2 _v;                                                           \
            _v.x = f2bf(SET[5][0]) | (f2bf(SET[5][1]) << 16);                   \
            _v.y = f2bf(SET[5][2]) | (f2bf(SET[5][3]) << 16);                   \
            *(uint2*)(_wb + 120) = _v;                                          \
        }                                                                       \
    }

    float sf0[6][4], sf1[6][4];   // two staging reg sets (slab s -> set s&1)

    // ---- prologue ----
    LOADS(sf0, xp[0] + (size_t)b * SLAB)            // slab 0 -> set 0
    WRITES(sf0, 0)                                  // buf 0
    LOADS(sf1, xp[1] + (size_t)b * SLAB)            // slab 1 -> set 1 (in flight)
    asm volatile("s_waitcnt lgkmcnt(0)" ::: "memory");
    __builtin_amdgcn_s_barrier();
    __builtin_amdgcn_sched_barrier(0);

#pragma unroll
    for (int i = 0; i < NOFF; ++i) {
        const unsigned char* bufR = &xs[(i % 3) * BUFB];

        // 1) B fragments for this offset (vector loads; wfrag L2-hot)
        bf16x8 bw[2][2];
#pragma unroll
        for (int kt = 0; kt < 2; ++kt)
#pragma unroll
            for (int of = 0; of < 2; ++of) {
                const int ot = oh * 2 + of;
                bw[kt][of] = *(const bf16x8*)&wfrag[(((i * 2 + kt) * 4 + ot) * 64 + lane) * 8];
            }

        // 2) issue loads for slab i+2 into set (i%2)  [freed last iter]
        if (i + 2 < NOFF) {
            if ((i & 1) == 0) { LOADS(sf0, xp[i + 2] + (size_t)b * SLAB) }
            else              { LOADS(sf1, xp[i + 2] + (size_t)b * SLAB) }
        }

        // 3) A-frag reads (12 x ds_read_b64) + 12 MFMA from buf[i%3]
        const int d = i - 4;
#pragma unroll
        for (int mt = 0; mt < 3; ++mt) {
            const bool valid = (unsigned)(wAv[mt] - d) < 9u;
            int q = valid ? (pAv[mt] - d) : ZR;
            if (q > ZR) q = ZR;                    // garbage rows: clamp in-bounds
            const unsigned char* rp = bufR + q * RSTB + lhi * 16;

#pragma unroll
            for (int kt = 0; kt < 2; ++kt) {
                int2 lo = *(const int2*)(rp + kt * 64);
                int2 hi = *(const int2*)(rp + kt * 64 + 8);
                int4 ai = { lo.x, lo.y, hi.x, hi.y };
                bf16x8 af = __builtin_bit_cast(bf16x8, ai);
                acc[mt][0] = __builtin_amdgcn_mfma_f32_16x16x32_bf16(af, bw[kt][0], acc[mt][0], 0, 0, 0);
                acc[mt][1] = __builtin_amdgcn_mfma_f32_16x16x32_bf16(af, bw[kt][1], acc[mt][1], 0, 0, 0);
            }
        }

        // 4) cvt + ds_write slab i+1 (set (i+1)%2, landed ~1 iter ago) -> buf[(i+1)%3]
        //    buf[(i+1)%3] was last READ at iter i-2 (two barriers ago) -> safe.
        if (i + 1 < NOFF) {
            if (((i + 1) & 1) == 0) { WRITES(sf0, (i + 1) % 3) }
            else                    { WRITES(sf1, (i + 1) % 3) }
            asm volatile("s_waitcnt lgkmcnt(0)" ::: "memory");
            __builtin_amdgcn_s_barrier();
            __builtin_amdgcn_sched_barrier(0);
        }
    }

    // store: D row p' (natural h*9+w), col o
    float* ob = out + (size_t)b * COUT * HW;
#pragma unroll
    for (int mt = 0; mt < 3; ++mt) {
#pragma unroll
        for (int of = 0; of < 2; ++of) {
            const int ocol = oh * 32 + of * 16 + l15;
#pragma unroll
            for (int jj = 0; jj < 4; ++jj) {
                const int pp = mh * 48 + mt * 16 + lhi * 4 + jj;
                if (pp < 81) ob[ocol * HW + pp] = acc[mt][of][jj];
            }
        }
    }
#undef LOADS
#undef WRITES
}

extern "C" void kernel_launch(void* const* d_in, const int* in_sizes, int n_in,
                              void* d_out, int out_size, void* d_ws, size_t ws_size,
                              hipStream_t stream) {
    const float* x[9];
    for (int i = 0; i < 9; ++i) x[i] = (const float*)d_in[i];
    const float* wts  = (const float*)d_in[9];
    const float* bias = (const float*)d_in[10];
    float* out = (float*)d_out;

    unsigned short* wfrag = (unsigned short*)d_ws;                    // 73728 B
    float* biasEff = (float*)((char*)d_ws + NOFF * 4096 * sizeof(unsigned short));

    prep_kernel<<<144, 256, 0, stream>>>(wts, bias, wfrag, biasEff);
    scatter_mfma8_kernel<<<1024, 256, 0, stream>>>(
        x[0], x[1], x[2], x[3], x[4], x[5], x[6], x[7], x[8],
        wfrag, biasEff, out);
}